// Round 2
// baseline (308.429 us; speedup 1.0000x reference)
//
#include <hip/hip_runtime.h>
#include <hip/hip_bf16.h>

// ---------------------------------------------------------------------------
// ShuffleRowAttention: B=16, N=1024, DIM=768, H=12, DH=64. fp32 in/out
// (runtime-detected). Round 8:
//  * QKV GEMM ported to the 256x256 / BK=64 / 8-wave 8-phase template
//    (T2 swizzle + T3/T4 phase pipeline + T5 setprio), plain HIP:
//    per K-tile 4 phases {ds_read quadrant | stage prefetch -> s_barrier ->
//    lgkmcnt(0)+sched_barrier -> setprio(1) 16xMFMA setprio(0) -> s_barrier},
//    raw s_barrier (prefetch survives barriers), single vmcnt(0) per K-tile
//    at the flip, stage issues front-loaded in phases 0-1 (~3 phases of
//    latency cover with depth-1 double buffering). LDS 128 KiB, 1 block/CU.
//  * gemm_bt<1> (output proj) and attn unchanged this round.
// ---------------------------------------------------------------------------

typedef __bf16 bf16x8 __attribute__((ext_vector_type(8)));
typedef __bf16 bf16x4 __attribute__((ext_vector_type(4)));
typedef float  f32x4  __attribute__((ext_vector_type(4)));

__device__ __forceinline__ f32x4 mfma16(bf16x8 a, bf16x8 b, f32x4 c) {
    return __builtin_amdgcn_mfma_f32_16x16x32_bf16(a, b, c, 0, 0, 0);
}

// async 16B/lane global->LDS: lds base wave-uniform; lane i deposits at +16*i.
__device__ __forceinline__ void async16(const void* g, void* l) {
    __builtin_amdgcn_global_load_lds(
        (const __attribute__((address_space(1))) unsigned int*)g,
        (__attribute__((address_space(3))) unsigned int*)l,
        16, 0, 0);
}

// ---------------------------------------------------------------------------
// dtype detector: fp32 data viewed as uint16 halves -> ~25% of low halves have
// exponent-field >= 0xC0; true bf16 N(0,1) never does. flag=1 -> fp32.
// ---------------------------------------------------------------------------
__global__ void detect_dtype(const unsigned short* __restrict__ raw, int* __restrict__ flag) {
    __shared__ int cnt;
    if (threadIdx.x == 0) cnt = 0;
    __syncthreads();
    int local = 0;
    for (int i = threadIdx.x; i < 2048; i += 256) {
        unsigned e = (raw[i] >> 7) & 0xFFu;
        if (e >= 0xC0u) local++;
    }
    atomicAdd(&cnt, local);
    __syncthreads();
    if (threadIdx.x == 0) *flag = (cnt > 16) ? 1 : 0;
}

__global__ void convert_to_bf16(const void* __restrict__ src, __bf16* __restrict__ dst,
                                int n4, const int* __restrict__ flag) {
    const int f = *flag;
    int i = blockIdx.x * blockDim.x + threadIdx.x;
    const int stride = gridDim.x * blockDim.x;
    if (f) {
        const float4* s = (const float4*)src;
        for (; i < n4; i += stride) {
            float4 v = s[i];
            bf16x4 o;
            o[0] = (__bf16)v.x; o[1] = (__bf16)v.y;
            o[2] = (__bf16)v.z; o[3] = (__bf16)v.w;
            *(bf16x4*)&dst[(size_t)i * 4] = o;
        }
    } else {
        const ushort4* s = (const ushort4*)src;
        for (; i < n4; i += stride) *(ushort4*)&dst[(size_t)i * 4] = s[i];
    }
}

__global__ void transpose_dyn(const void* __restrict__ in, __bf16* __restrict__ out,
                              int R, int C, const int* __restrict__ flag) {
    __shared__ __bf16 tile[64][65];
    const int f = *flag;
    const int c0 = blockIdx.x * 64, r0 = blockIdx.y * 64;
    const int tx = threadIdx.x, ty = threadIdx.y;
#pragma unroll
    for (int k = 0; k < 16; ++k) {
        int r = ty + 4 * k;
        size_t idx = (size_t)(r0 + r) * C + c0 + tx;
        tile[r][tx] = f ? (__bf16)((const float*)in)[idx] : ((const __bf16*)in)[idx];
    }
    __syncthreads();
#pragma unroll
    for (int k = 0; k < 16; ++k) {
        int cc = ty + 4 * k;
        out[(size_t)(c0 + cc) * R + r0 + tx] = tile[tx][cc];
    }
}

__global__ void transpose_v(const __bf16* __restrict__ qkv, __bf16* __restrict__ vt) {
    __shared__ __bf16 tile[64][65];
    const int bh = blockIdx.y;
    const int b = bh / 12, h = bh % 12;
    const int n0 = blockIdx.x * 64;
    const int tx = threadIdx.x, ty = threadIdx.y;
#pragma unroll
    for (int k = 0; k < 16; ++k) {
        int n = ty + 4 * k;
        tile[n][tx] = qkv[((size_t)b * 1024 + n0 + n) * 2304 + 1536 + h * 64 + tx];
    }
    __syncthreads();
#pragma unroll
    for (int k = 0; k < 16; ++k) {
        int d = ty + 4 * k;
        vt[((size_t)bh * 64 + d) * 1024 + n0 + tx] = tile[tx][d];
    }
}

// ---------------------------------------------------------------------------
// 256x256 8-phase GEMM: C[M x N] = A[M x K] * Bt[N x K]^T, bf16 in/out, fp32
// acc. BK=64, 8 waves (2M x 4N), 512 threads, 128 KiB LDS double-buffered.
// LDS layout (byte offsets): A buf0 @0, A buf1 @32768, B buf0 @65536,
// B buf1 @98304. Tiles stored [256 rows][64 cols] bf16 with per-row XOR
// swizzle: 8-elem chunk j of row r lands at chunk j^(r&7) (conflict-free
// ds_read_b128; staged via pre-swizzled global source + linear LDS dest).
// Per K-tile 4 phases, one 64x32 C-quadrant (16 MFMA) each:
//   ph0: read af[0..3][*] bf[0..1][*]; stage next A; Q(0,0)
//   ph1: read bf[2..3][*];             stage next B; Q(0,1)
//   ph2: read af[4..7][*];                           Q(1,0)
//   ph3: (regs live)                                 Q(1,1); vmcnt(0); flip
// ---------------------------------------------------------------------------
__global__ __launch_bounds__(512, 2)
void gemm256_bt(const __bf16* __restrict__ A, int lda,
                const __bf16* __restrict__ Bt, int ldb,
                __bf16* __restrict__ Cout, int ldc, int K) {
    __shared__ __align__(16) char smem[131072];
    const int tid  = threadIdx.x;
    const int wid  = tid >> 6;
    const int lane = tid & 63;
    const int quad = lane >> 4;
    const int l15  = lane & 15;
    const int wr   = wid >> 2;   // 0..1: M half (128 rows)
    const int wc   = wid & 3;    // 0..3: N quarter (64 cols)
    const int bm = blockIdx.x * 256;
    const int bn = blockIdx.y * 256;
    const int srow8  = lane >> 3;
    const int sslot8 = lane & 7;

    // fragment read offsets (bytes within a tile buffer), kk = 0/1:
    // row = l15 (mod 16-block), chunk = (kk*4+quad) ^ (l15&7)
    const int offk[2] = { l15 * 128 + (((quad    ) ^ (l15 & 7)) * 16),
                          l15 * 128 + (((quad | 4) ^ (l15 & 7)) * 16) };

    // staging: chunk p of this wave covers tile rows (wid*4+p)*8 .. +8.
    // lane's global col chunk = sslot8 ^ srow8 (row&7 == srow8, 8-row aligned).
    const int cchunk = (sslot8 ^ srow8) * 8;
    const __bf16* gA[4];
    const __bf16* gB[4];
#pragma unroll
    for (int p = 0; p < 4; ++p) {
        int r = (wid * 4 + p) * 8 + srow8;
        gA[p] = A  + (size_t)(bm + r) * lda + cchunk;
        gB[p] = Bt + (size_t)(bn + r) * ldb + cchunk;
    }

    f32x4 acc[8][4];
#pragma unroll
    for (int i = 0; i < 8; ++i)
#pragma unroll
        for (int j = 0; j < 4; ++j) acc[i][j] = (f32x4)0.0f;

    // ---- prologue: stage K-tile 0 into buf0 ----
#pragma unroll
    for (int p = 0; p < 4; ++p) {
        async16(gA[p], smem + (wid * 4 + p) * 1024);
        async16(gB[p], smem + 65536 + (wid * 4 + p) * 1024);
        gA[p] += 64; gB[p] += 64;
    }
    asm volatile("s_waitcnt vmcnt(0)" ::: "memory");
    __builtin_amdgcn_s_barrier();

    const int nkt = K >> 6;
    int cur = 0;
#pragma unroll 1
    for (int kt = 0; kt < nkt; ++kt) {
        const bool notlast = (kt != nkt - 1);
        const char* aRd = smem + cur + wr * 16384;
        const char* bRd = smem + 65536 + cur + wc * 8192;
        char* aSt = smem + (cur ^ 32768);
        char* bSt = smem + 65536 + (cur ^ 32768);
        bf16x8 af[4][2], bfr[4][2];

        // ================= phase 0: Q(0,0) =================
#pragma unroll
        for (int i = 0; i < 4; ++i)
#pragma unroll
            for (int kk = 0; kk < 2; ++kk)
                af[i][kk] = *(const bf16x8*)(aRd + offk[kk] + i * 2048);
#pragma unroll
        for (int j = 0; j < 2; ++j)
#pragma unroll
            for (int kk = 0; kk < 2; ++kk)
                bfr[j][kk] = *(const bf16x8*)(bRd + offk[kk] + j * 2048);
        if (notlast) {
#pragma unroll
            for (int p = 0; p < 4; ++p) {
                async16(gA[p], aSt + (wid * 4 + p) * 1024);
                gA[p] += 64;
            }
        }
        __builtin_amdgcn_s_barrier();
        asm volatile("s_waitcnt lgkmcnt(0)" ::: "memory");
        __builtin_amdgcn_sched_barrier(0);
        __builtin_amdgcn_s_setprio(1);
#pragma unroll
        for (int i = 0; i < 4; ++i)
#pragma unroll
            for (int j = 0; j < 2; ++j)
#pragma unroll
                for (int kk = 0; kk < 2; ++kk)
                    acc[i][j] = mfma16(af[i][kk], bfr[j][kk], acc[i][j]);
        __builtin_amdgcn_s_setprio(0);
        __builtin_amdgcn_s_barrier();

        // ================= phase 1: Q(0,1) =================
#pragma unroll
        for (int j = 0; j < 2; ++j)
#pragma unroll
            for (int kk = 0; kk < 2; ++kk)
                bfr[2 + j][kk] = *(const bf16x8*)(bRd + offk[kk] + (2 + j) * 2048);
        if (notlast) {
#pragma unroll
            for (int p = 0; p < 4; ++p) {
                async16(gB[p], bSt + (wid * 4 + p) * 1024);
                gB[p] += 64;
            }
        }
        __builtin_amdgcn_s_barrier();
        asm volatile("s_waitcnt lgkmcnt(0)" ::: "memory");
        __builtin_amdgcn_sched_barrier(0);
        __builtin_amdgcn_s_setprio(1);
#pragma unroll
        for (int i = 0; i < 4; ++i)
#pragma unroll
            for (int j = 0; j < 2; ++j)
#pragma unroll
                for (int kk = 0; kk < 2; ++kk)
                    acc[i][2 + j] = mfma16(af[i][kk], bfr[2 + j][kk], acc[i][2 + j]);
        __builtin_amdgcn_s_setprio(0);
        __builtin_amdgcn_s_barrier();

        // ================= phase 2: Q(1,0) =================
#pragma unroll
        for (int i = 0; i < 4; ++i)
#pragma unroll
            for (int kk = 0; kk < 2; ++kk)
                af[i][kk] = *(const bf16x8*)(aRd + offk[kk] + (4 + i) * 2048);
        __builtin_amdgcn_s_barrier();
        asm volatile("s_waitcnt lgkmcnt(0)" ::: "memory");
        __builtin_amdgcn_sched_barrier(0);
        __builtin_amdgcn_s_setprio(1);
#pragma unroll
        for (int i = 0; i < 4; ++i)
#pragma unroll
            for (int j = 0; j < 2; ++j)
#pragma unroll
                for (int kk = 0; kk < 2; ++kk)
                    acc[4 + i][j] = mfma16(af[i][kk], bfr[j][kk], acc[4 + i][j]);
        __builtin_amdgcn_s_setprio(0);
        __builtin_amdgcn_s_barrier();

        // ================= phase 3: Q(1,1) =================
        __builtin_amdgcn_s_setprio(1);
#pragma unroll
        for (int i = 0; i < 4; ++i)
#pragma unroll
            for (int j = 0; j < 2; ++j)
#pragma unroll
                for (int kk = 0; kk < 2; ++kk)
                    acc[4 + i][2 + j] = mfma16(af[i][kk], bfr[2 + j][kk], acc[4 + i][2 + j]);
        __builtin_amdgcn_s_setprio(0);
        asm volatile("s_waitcnt vmcnt(0)" ::: "memory");
        __builtin_amdgcn_s_barrier();
        cur ^= 32768;
    }

    // ---- epilogue: 8 chunks of 32 rows via LDS cs=[32][264] bf16 ----
    __bf16* cs = (__bf16*)smem;
#pragma unroll 1
    for (int c = 0; c < 8; ++c) {
        __syncthreads();
        if (wr == (c >> 2)) {
            int mbase = (c & 3) * 2;
#pragma unroll
            for (int mloc = 0; mloc < 2; ++mloc) {
#pragma unroll
                for (int ni = 0; ni < 4; ++ni) {
                    int col = wc * 64 + ni * 16 + l15;
#pragma unroll
                    for (int rg = 0; rg < 4; ++rg)
                        cs[(mloc * 16 + quad * 4 + rg) * 264 + col] =
                            (__bf16)acc[mbase + mloc][ni][rg];
                }
            }
        }
        __syncthreads();
#pragma unroll
        for (int p = 0; p < 2; ++p) {
            int row  = p * 16 + (tid >> 5);
            int colc = tid & 31;
            bf16x8 v = *(const bf16x8*)&cs[row * 264 + colc * 8];
            *(bf16x8*)&Cout[(size_t)(bm + c * 32 + row) * ldc + bn + colc * 8] = v;
        }
    }
}

// ---------------------------------------------------------------------------
// GEMM: C[M x N] = A[M x K] * Bt[N x K]^T (+ bias); bf16 in, fp32 acc.
// 128x128 tile, BK=32, 4 waves, 16x16x32 MFMA, async16 staging w/ XOR swizzle.
// Epilogue: stage through LDS (aliases lsA/lsB), store coalesced row segments.
// MODE 0: C bf16, no bias. MODE 1: C/bias dtype per flag.
// ---------------------------------------------------------------------------
template <int MODE>
__global__ __launch_bounds__(256)
void gemm_bt(const __bf16* __restrict__ A, int lda,
             const __bf16* __restrict__ Bt,
             const void* __restrict__ bias,
             void* __restrict__ Cout, int ldc,
             int K, const int* __restrict__ flag) {
    __shared__ __align__(16) char smem[16384];
    __bf16* lsA = (__bf16*)smem;            // 128 x 32
    __bf16* lsB = (__bf16*)(smem + 8192);   // 128 x 32
    const int tid  = threadIdx.x;
    const int wid  = tid >> 6;
    const int lane = tid & 63;
    const int quad = lane >> 4;
    const int l15  = lane & 15;
    const int bm = blockIdx.x * 128;
    const int bn = blockIdx.y * 128;
    const int wm = (wid & 1) * 64;
    const int wn = (wid >> 1) * 64;
    const int srow  = lane >> 2;
    const int sslot = lane & 3;

    f32x4 acc[4][4];
#pragma unroll
    for (int i = 0; i < 4; ++i)
#pragma unroll
        for (int j = 0; j < 4; ++j) acc[i][j] = (f32x4)0.0f;

    for (int k0 = 0; k0 < K; k0 += 32) {
        __syncthreads();
#pragma unroll
        for (int is = 0; is < 2; ++is) {
            int r  = is * 64 + wid * 16 + srow;
            int gc = k0 + ((sslot ^ ((r >> 1) & 3)) << 3);
            async16(A + (size_t)(bm + r) * lda + gc, &lsA[(is * 64 + wid * 16) * 32]);
        }
#pragma unroll
        for (int is = 0; is < 2; ++is) {
            int r  = is * 64 + wid * 16 + srow;
            int gc = k0 + ((sslot ^ ((r >> 1) & 3)) << 3);
            async16(Bt + (size_t)(bn + r) * K + gc, &lsB[(is * 64 + wid * 16) * 32]);
        }
        __syncthreads();

        bf16x8 af[4], bfr[4];
#pragma unroll
        for (int mi = 0; mi < 4; ++mi) {
            int r = wm + mi * 16 + l15;
            af[mi] = *(const bf16x8*)&lsA[r * 32 + (quad ^ ((r >> 1) & 3)) * 8];
        }
#pragma unroll
        for (int ni = 0; ni < 4; ++ni) {
            int r = wn + ni * 16 + l15;
            bfr[ni] = *(const bf16x8*)&lsB[r * 32 + (quad ^ ((r >> 1) & 3)) * 8];
        }
#pragma unroll
        for (int mi = 0; mi < 4; ++mi)
#pragma unroll
            for (int ni = 0; ni < 4; ++ni)
                acc[mi][ni] = mfma16(af[mi], bfr[ni], acc[mi][ni]);
    }

    // ---- epilogue: bias add in-register, then LDS-staged coalesced stores ----
    const int f = (MODE == 1) ? *flag : 0;
    if (MODE == 1) {
#pragma unroll
        for (int ni = 0; ni < 4; ++ni) {
            int col = bn + wn + ni * 16 + l15;
            float bv = f ? ((const float*)bias)[col] : (float)((const __bf16*)bias)[col];
#pragma unroll
            for (int mi = 0; mi < 4; ++mi)
#pragma unroll
                for (int rg = 0; rg < 4; ++rg) acc[mi][ni][rg] += bv;
        }
    }

    if (MODE == 0 || !f) {
        // bf16 output: 4 chunks of 32 rows; cs = [32][136] bf16 (8704 B)
        __bf16* cs = (__bf16*)smem;
#pragma unroll
        for (int c = 0; c < 4; ++c) {
            __syncthreads();
            if (wm == (c >> 1) * 64) {
                int mb = (c & 1) * 2;
#pragma unroll
                for (int mloc = 0; mloc < 2; ++mloc) {
                    int rowc = mloc * 16 + quad * 4;
#pragma unroll
                    for (int ni = 0; ni < 4; ++ni) {
                        int col = wn + ni * 16 + l15;
#pragma unroll
                        for (int rg = 0; rg < 4; ++rg)
                            cs[(rowc + rg) * 136 + col] = (__bf16)acc[mb + mloc][ni][rg];
                    }
                }
            }
            __syncthreads();
#pragma unroll
            for (int p = 0; p < 2; ++p) {
                int row  = p * 16 + (tid >> 4);
                int colc = tid & 15;
                bf16x8 v = *(const bf16x8*)&cs[row * 136 + colc * 8];
                *(bf16x8*)((__bf16*)Cout + (size_t)(bm + c * 32 + row) * ldc + bn + colc * 8) = v;
            }
        }
    } else {
        // fp32 output: 8 chunks of 16 rows; cs = [16][132] float (8448 B)
        float* cs = (float*)smem;
#pragma unroll
        for (int c = 0; c < 8; ++c) {
            __syncthreads();
            if (wm == (c >> 2) * 64) {
                int mi = c & 3;
                int rowc = quad * 4;
#pragma unroll
                for (int ni = 0; ni < 4; ++ni) {
                    int col = wn + ni * 16 + l15;
#pragma unroll
                    for (int rg = 0; rg < 4; ++rg)
                        cs[(rowc + rg) * 132 + col] = acc[mi][ni][rg];
                }
            }
            __syncthreads();
#pragma unroll
            for (int p = 0; p < 2; ++p) {
                int row  = p * 8 + (tid >> 5);
                int colc = tid & 31;
                float4 v = *(const float4*)&cs[row * 132 + colc * 4];
                *(float4*)((float*)Cout + (size_t)(bm + c * 16 + row) * ldc + bn + colc * 4) = v;
            }
        }
    }
}

// ---------------------------------------------------------------------------
// Flash attention, S^T formulation, async16 staging. Grid (B*H, N/128) --
// bh is blockIdx.x so id%8 = bh%8: all q-tiles of a head pin to one XCD.
// Round 7: register-relaxed, address-hoisted, half-split K-step.
// ---------------------------------------------------------------------------
__global__ __launch_bounds__(256, 2)
void attn(const __bf16* qkv, const __bf16* __restrict__ vt,
          const int* __restrict__ perm, __bf16* O, int ldo) {
    __shared__ __align__(16) char smem[38912];
    __bf16* Qs = (__bf16*)smem;              // 128 x 64 (alive until qf loaded)
    __bf16* Ks = (__bf16*)smem;              // 64 x 64  (aliases Qs)
    __bf16* Vs = (__bf16*)(smem + 8192);     // 64 x 64  (rows = dh)
    __bf16* Ps = (__bf16*)(smem + 16384);    // 4 waves x [32 x 88]

    const int tid  = threadIdx.x;
    const int wid  = tid >> 6;
    const int lane = tid & 63;
    const int quad = lane >> 4;
    const int l15  = lane & 15;
    const int bh = blockIdx.x;
    const int q0 = blockIdx.y * 128;
    const int b = bh / 12, h = bh % 12;
    const size_t row_base = (size_t)b * 1024;
    const int qcol = h * 64;
    const int kcol = 768 + h * 64;
    const int srow8  = lane >> 3;
    const int sslot8 = lane & 7;
    __bf16* Pw = Ps + wid * (32 * 88);

    // ---- stage Q (perm-gathered rows) ----
#pragma unroll
    for (int is = 0; is < 4; ++is) {
        int r = is * 32 + wid * 8 + srow8;
        int gr = perm[q0 + r];
        int chunk = sslot8 ^ (r & 7);
        async16(qkv + (row_base + gr) * 2304 + qcol + chunk * 8,
                &Qs[(is * 32 + wid * 8) * 64]);
    }
    __syncthreads();

    bf16x8 qf[2][2];
#pragma unroll
    for (int mi = 0; mi < 2; ++mi) {
        int r = wid * 32 + mi * 16 + l15;
#pragma unroll
        for (int ks = 0; ks < 2; ++ks)
            qf[mi][ks] = *(const bf16x8*)&Qs[r * 64 + (((ks * 4 + quad) ^ (r & 7)) * 8)];
    }

    // ---- loop-invariant LDS element offsets ----
    const int off0 = l15 * 64 + (((0 * 4 + quad) ^ (l15 & 7)) * 8); // ks/ks2 = 0
    const int off1 = l15 * 64 + (((1 * 4 + quad) ^ (l15 & 7)) * 8); // ks/ks2 = 1
    const int pwb  = l15 * 88 + quad * 4;   // + mi*1408 + ki*16 (immediates)
    const int pfb  = l15 * 88 + quad * 8;   // + mi*1408 + ks2*32 (immediates)

    // ---- held global staging pointers (incremented per kt) ----
    const int rK = wid * 8 + srow8;                 // +32 for second chunk
    const int ck = sslot8 ^ (rK & 7);               // (is*32)&7 == 0
    const __bf16* kg0 = qkv + (row_base + rK) * 2304 + kcol + ck * 8;
    const __bf16* kg1 = kg0 + (size_t)32 * 2304;
    const __bf16* vg0 = vt + ((size_t)bh * 64 + rK) * 1024 + ck * 8;
    const __bf16* vg1 = vg0 + (size_t)32 * 1024;

    f32x4 acco[2][4];
#pragma unroll
    for (int mi = 0; mi < 2; ++mi)
#pragma unroll
        for (int ni = 0; ni < 4; ++ni) acco[mi][ni] = (f32x4)0.0f;
    float lsum[2] = {0.0f, 0.0f};

    const float cfac = 0.125f * 1.44269504088896340736f;

    for (int kt = 0; kt < 16; ++kt) {
        __syncthreads();
        async16(kg0, &Ks[(wid * 8) * 64]);
        async16(kg1, &Ks[(32 + wid * 8) * 64]);
        async16(vg0, &Vs[(wid * 8) * 64]);
        async16(vg1, &Vs[(32 + wid * 8) * 64]);
        kg0 += (size_t)64 * 2304;
        kg1 += (size_t)64 * 2304;
        vg0 += 64;
        vg1 += 64;
        __syncthreads();

#pragma unroll
        for (int half = 0; half < 2; ++half) {
            // ---- QK^T for ki = half*2 .. half*2+1 ----
            f32x4 accs[2][2];
#pragma unroll
            for (int ki = 0; ki < 2; ++ki)
#pragma unroll
                for (int mi = 0; mi < 2; ++mi) accs[ki][mi] = (f32x4)0.0f;
#pragma unroll
            for (int ks = 0; ks < 2; ++ks) {
                const int off = ks ? off1 : off0;
                bf16x8 kf0 = *(const bf16x8*)&Ks[(half * 2 + 0) * 1024 + off];
                bf16x8 kf1 = *(const bf16x8*)&Ks[(half * 2 + 1) * 1024 + off];
                accs[0][0] = mfma16(kf0, qf[0][ks], accs[0][0]);
                accs[0][1] = mfma16(kf0, qf[1][ks], accs[0][1]);
                accs[1][0] = mfma16(kf1, qf[0][ks], accs[1][0]);
                accs[1][1] = mfma16(kf1, qf[1][ks], accs[1][1]);
            }

            // ---- softmax (static bias -8; cancels in normalization) ----
#pragma unroll
            for (int ki = 0; ki < 2; ++ki)
#pragma unroll
                for (int mi = 0; mi < 2; ++mi) {
                    bf16x4 pk;
                    float s0 = __builtin_amdgcn_exp2f(accs[ki][mi][0] * cfac - 8.0f);
                    float s1 = __builtin_amdgcn_exp2f(accs[ki][mi][1] * cfac - 8.0f);
                    float s2 = __builtin_amdgcn_exp2f(accs[ki][mi][2] * cfac - 8.0f);
                    float s3 = __builtin_amdgcn_exp2f(accs[ki][mi][3] * cfac - 8.0f);
                    pk[0] = (__bf16)s0; pk[1] = (__bf16)s1;
                    pk[2] = (__bf16)s2; pk[3] = (__bf16)s3;
                    lsum[mi] += (s0 + s1) + (s2 + s3);
                    *(bf16x4*)&Pw[pwb + mi * 1408 + (half * 2 + ki) * 16] = pk;
                }

            // ---- PV for ks2 = half (same-wave LDS RAW; lgkmcnt orders it) ----
            {
                bf16x8 pf0 = *(const bf16x8*)&Pw[pfb + 0 * 1408 + half * 32];
                bf16x8 pf1 = *(const bf16x8*)&Pw[pfb + 1 * 1408 + half * 32];
                const int offv = half ? off1 : off0;
#pragma unroll
                for (int ni = 0; ni < 4; ++ni) {
                    bf16x8 vf = *(const bf16x8*)&Vs[ni * 1024 + offv];
                    acco[0][ni] = mfma16(pf0, vf, acco[0][ni]);
                    acco[1][ni] = mfma16(pf1, vf, acco[1][ni]);
                }
            }
        }
    }

#pragma unroll
    for (int off = 16; off < 64; off <<= 1) {
        lsum[0] += __shfl_xor(lsum[0], off, 64);
        lsum[1] += __shfl_xor(lsum[1], off, 64);
    }

#pragma unroll
    for (int mi = 0; mi < 2; ++mi) {
#pragma unroll
        for (int rg = 0; rg < 4; ++rg) {
            float inv = 1.0f / __shfl(lsum[mi], quad * 4 + rg, 64);
            int orow = q0 + wid * 32 + mi * 16 + quad * 4 + rg;
#pragma unroll
            for (int ni = 0; ni < 4; ++ni) {
                int ocol = h * 64 + ni * 16 + l15;
                O[(row_base + orow) * (size_t)ldo + ocol] = (__bf16)(acco[mi][ni][rg] * inv);
            }
        }
    }
}

// ---------------------------------------------------------------------------
// Workspace layout (bytes), total ~130.5 MB (see round-3 comment).
// ---------------------------------------------------------------------------
extern "C" void kernel_launch(void* const* d_in, const int* in_sizes, int n_in,
                              void* d_out, int out_size, void* d_ws, size_t ws_size,
                              hipStream_t stream) {
    (void)in_sizes; (void)n_in; (void)out_size; (void)ws_size;
    const void* x_raw    = d_in[0];
    const void* Wqkv_raw = d_in[1];
    const void* Wout_raw = d_in[2];
    const void* bout_raw = d_in[3];
    const int*  perm     = (const int*)d_in[4];

    char* ws = (char*)d_ws;
    int*    flag = (int*)ws;
    __bf16* Xc   = (__bf16*)(ws + 256);
    __bf16* QKV  = (__bf16*)(ws + 25166080);
    __bf16* Vt   = (__bf16*)(ws + 100663552);
    __bf16* Wqt  = (__bf16*)(ws + 125829376);
    __bf16* Wot  = (__bf16*)(ws + 129368320);
    __bf16* Obuf = QKV + 1536; // O[n][768] in QKV's V columns, ld 2304

    detect_dtype<<<1, 256, 0, stream>>>((const unsigned short*)x_raw, flag);
    convert_to_bf16<<<2048, 256, 0, stream>>>(x_raw, Xc, 16384 * 768 / 4, flag);
    transpose_dyn<<<dim3(36, 12), dim3(64, 4), 0, stream>>>(Wqkv_raw, Wqt, 768, 2304, flag);
    transpose_dyn<<<dim3(12, 12), dim3(64, 4), 0, stream>>>(Wout_raw, Wot, 768, 768, flag);
    gemm256_bt<<<dim3(64, 9), 512, 0, stream>>>(Xc, 768, Wqt, 768, QKV, 2304, 768);
    transpose_v<<<dim3(16, 192), dim3(64, 4), 0, stream>>>(QKV, Vt);
    attn<<<dim3(192, 8), 256, 0, stream>>>(QKV, Vt, perm, Obuf, 2304);
    gemm_bt<1><<<dim3(128, 6), 256, 0, stream>>>(Obuf, 2304, Wot, bout_raw, d_out, 768, 768, flag);
}

// Round 3
// 219.699 us; speedup vs baseline: 1.4039x; 1.4039x over previous
//
#include <hip/hip_runtime.h>
#include <hip/hip_bf16.h>

// ---------------------------------------------------------------------------
// ShuffleRowAttention: B=16, N=1024, DIM=768, H=12, DH=64. fp32 in/out
// (runtime-detected). Round 9:
//  * Round-8 post-mortem: gemm256's epilogue used `#pragma unroll 1` with
//    acc[(c&3)*2+..] -- a RUNTIME index into the ext_vector acc array ->
//    whole acc array demoted to scratch (rule #20). Evidence: WRITE_SIZE was
//    exactly 5x C bytes = +1024 B/thread (= sizeof(acc)+frags), FETCH +74 MB,
//    MfmaUtil 14%. Fix: fully unroll the epilogue chunk loop so every acc
//    access is compile-time-static. No other change (clean attribution of
//    the 8-phase schedule itself).
// ---------------------------------------------------------------------------

typedef __bf16 bf16x8 __attribute__((ext_vector_type(8)));
typedef __bf16 bf16x4 __attribute__((ext_vector_type(4)));
typedef float  f32x4  __attribute__((ext_vector_type(4)));

__device__ __forceinline__ f32x4 mfma16(bf16x8 a, bf16x8 b, f32x4 c) {
    return __builtin_amdgcn_mfma_f32_16x16x32_bf16(a, b, c, 0, 0, 0);
}

// async 16B/lane global->LDS: lds base wave-uniform; lane i deposits at +16*i.
__device__ __forceinline__ void async16(const void* g, void* l) {
    __builtin_amdgcn_global_load_lds(
        (const __attribute__((address_space(1))) unsigned int*)g,
        (__attribute__((address_space(3))) unsigned int*)l,
        16, 0, 0);
}

// ---------------------------------------------------------------------------
// dtype detector: fp32 data viewed as uint16 halves -> ~25% of low halves have
// exponent-field >= 0xC0; true bf16 N(0,1) never does. flag=1 -> fp32.
// ---------------------------------------------------------------------------
__global__ void detect_dtype(const unsigned short* __restrict__ raw, int* __restrict__ flag) {
    __shared__ int cnt;
    if (threadIdx.x == 0) cnt = 0;
    __syncthreads();
    int local = 0;
    for (int i = threadIdx.x; i < 2048; i += 256) {
        unsigned e = (raw[i] >> 7) & 0xFFu;
        if (e >= 0xC0u) local++;
    }
    atomicAdd(&cnt, local);
    __syncthreads();
    if (threadIdx.x == 0) *flag = (cnt > 16) ? 1 : 0;
}

__global__ void convert_to_bf16(const void* __restrict__ src, __bf16* __restrict__ dst,
                                int n4, const int* __restrict__ flag) {
    const int f = *flag;
    int i = blockIdx.x * blockDim.x + threadIdx.x;
    const int stride = gridDim.x * blockDim.x;
    if (f) {
        const float4* s = (const float4*)src;
        for (; i < n4; i += stride) {
            float4 v = s[i];
            bf16x4 o;
            o[0] = (__bf16)v.x; o[1] = (__bf16)v.y;
            o[2] = (__bf16)v.z; o[3] = (__bf16)v.w;
            *(bf16x4*)&dst[(size_t)i * 4] = o;
        }
    } else {
        const ushort4* s = (const ushort4*)src;
        for (; i < n4; i += stride) *(ushort4*)&dst[(size_t)i * 4] = s[i];
    }
}

__global__ void transpose_dyn(const void* __restrict__ in, __bf16* __restrict__ out,
                              int R, int C, const int* __restrict__ flag) {
    __shared__ __bf16 tile[64][65];
    const int f = *flag;
    const int c0 = blockIdx.x * 64, r0 = blockIdx.y * 64;
    const int tx = threadIdx.x, ty = threadIdx.y;
#pragma unroll
    for (int k = 0; k < 16; ++k) {
        int r = ty + 4 * k;
        size_t idx = (size_t)(r0 + r) * C + c0 + tx;
        tile[r][tx] = f ? (__bf16)((const float*)in)[idx] : ((const __bf16*)in)[idx];
    }
    __syncthreads();
#pragma unroll
    for (int k = 0; k < 16; ++k) {
        int cc = ty + 4 * k;
        out[(size_t)(c0 + cc) * R + r0 + tx] = tile[tx][cc];
    }
}

__global__ void transpose_v(const __bf16* __restrict__ qkv, __bf16* __restrict__ vt) {
    __shared__ __bf16 tile[64][65];
    const int bh = blockIdx.y;
    const int b = bh / 12, h = bh % 12;
    const int n0 = blockIdx.x * 64;
    const int tx = threadIdx.x, ty = threadIdx.y;
#pragma unroll
    for (int k = 0; k < 16; ++k) {
        int n = ty + 4 * k;
        tile[n][tx] = qkv[((size_t)b * 1024 + n0 + n) * 2304 + 1536 + h * 64 + tx];
    }
    __syncthreads();
#pragma unroll
    for (int k = 0; k < 16; ++k) {
        int d = ty + 4 * k;
        vt[((size_t)bh * 64 + d) * 1024 + n0 + tx] = tile[tx][d];
    }
}

// ---------------------------------------------------------------------------
// 256x256 8-phase GEMM: C[M x N] = A[M x K] * Bt[N x K]^T, bf16 in/out, fp32
// acc. BK=64, 8 waves (2M x 4N), 512 threads, 128 KiB LDS double-buffered.
// LDS layout (byte offsets): A buf0 @0, A buf1 @32768, B buf0 @65536,
// B buf1 @98304. Tiles stored [256 rows][64 cols] bf16 with per-row XOR
// swizzle: 8-elem chunk j of row r lands at chunk j^(r&7) (conflict-free
// ds_read_b128; staged via pre-swizzled global source + linear LDS dest).
// Per K-tile 4 phases, one 64x32 C-quadrant (16 MFMA) each:
//   ph0: read af[0..3][*] bf[0..1][*]; stage next A; Q(0,0)
//   ph1: read bf[2..3][*];             stage next B; Q(0,1)
//   ph2: read af[4..7][*];                           Q(1,0)
//   ph3: (regs live)                                 Q(1,1); vmcnt(0); flip
// Epilogue: FULLY UNROLLED (static acc indices -- rule #20).
// ---------------------------------------------------------------------------
__global__ __launch_bounds__(512, 2)
void gemm256_bt(const __bf16* __restrict__ A, int lda,
                const __bf16* __restrict__ Bt, int ldb,
                __bf16* __restrict__ Cout, int ldc, int K) {
    __shared__ __align__(16) char smem[131072];
    const int tid  = threadIdx.x;
    const int wid  = tid >> 6;
    const int lane = tid & 63;
    const int quad = lane >> 4;
    const int l15  = lane & 15;
    const int wr   = wid >> 2;   // 0..1: M half (128 rows)
    const int wc   = wid & 3;    // 0..3: N quarter (64 cols)
    const int bm = blockIdx.x * 256;
    const int bn = blockIdx.y * 256;
    const int srow8  = lane >> 3;
    const int sslot8 = lane & 7;

    // fragment read offsets (bytes within a tile buffer), kk = 0/1:
    // row = l15 (mod 16-block), chunk = (kk*4+quad) ^ (l15&7)
    const int offk0 = l15 * 128 + (((quad    ) ^ (l15 & 7)) * 16);
    const int offk1 = l15 * 128 + (((quad | 4) ^ (l15 & 7)) * 16);

    // staging: chunk p of this wave covers tile rows (wid*4+p)*8 .. +8.
    // lane's global col chunk = sslot8 ^ srow8 (row&7 == srow8, 8-row aligned).
    const int cchunk = (sslot8 ^ srow8) * 8;
    const __bf16* gA[4];
    const __bf16* gB[4];
#pragma unroll
    for (int p = 0; p < 4; ++p) {
        int r = (wid * 4 + p) * 8 + srow8;
        gA[p] = A  + (size_t)(bm + r) * lda + cchunk;
        gB[p] = Bt + (size_t)(bn + r) * ldb + cchunk;
    }

    f32x4 acc[8][4];
#pragma unroll
    for (int i = 0; i < 8; ++i)
#pragma unroll
        for (int j = 0; j < 4; ++j) acc[i][j] = (f32x4)0.0f;

    // ---- prologue: stage K-tile 0 into buf0 ----
#pragma unroll
    for (int p = 0; p < 4; ++p) {
        async16(gA[p], smem + (wid * 4 + p) * 1024);
        async16(gB[p], smem + 65536 + (wid * 4 + p) * 1024);
        gA[p] += 64; gB[p] += 64;
    }
    asm volatile("s_waitcnt vmcnt(0)" ::: "memory");
    __builtin_amdgcn_s_barrier();

    const int nkt = K >> 6;
    int cur = 0;
#pragma unroll 1
    for (int kt = 0; kt < nkt; ++kt) {
        const bool notlast = (kt != nkt - 1);
        const char* aRd = smem + cur + wr * 16384;
        const char* bRd = smem + 65536 + cur + wc * 8192;
        char* aSt = smem + (cur ^ 32768);
        char* bSt = smem + 65536 + (cur ^ 32768);
        bf16x8 af[4][2], bfr[4][2];

        // ================= phase 0: Q(0,0) =================
#pragma unroll
        for (int i = 0; i < 4; ++i) {
            af[i][0] = *(const bf16x8*)(aRd + offk0 + i * 2048);
            af[i][1] = *(const bf16x8*)(aRd + offk1 + i * 2048);
        }
#pragma unroll
        for (int j = 0; j < 2; ++j) {
            bfr[j][0] = *(const bf16x8*)(bRd + offk0 + j * 2048);
            bfr[j][1] = *(const bf16x8*)(bRd + offk1 + j * 2048);
        }
        if (notlast) {
#pragma unroll
            for (int p = 0; p < 4; ++p) {
                async16(gA[p], aSt + (wid * 4 + p) * 1024);
                gA[p] += 64;
            }
        }
        __builtin_amdgcn_s_barrier();
        asm volatile("s_waitcnt lgkmcnt(0)" ::: "memory");
        __builtin_amdgcn_sched_barrier(0);
        __builtin_amdgcn_s_setprio(1);
#pragma unroll
        for (int i = 0; i < 4; ++i)
#pragma unroll
            for (int j = 0; j < 2; ++j)
#pragma unroll
                for (int kk = 0; kk < 2; ++kk)
                    acc[i][j] = mfma16(af[i][kk], bfr[j][kk], acc[i][j]);
        __builtin_amdgcn_s_setprio(0);
        __builtin_amdgcn_s_barrier();

        // ================= phase 1: Q(0,1) =================
#pragma unroll
        for (int j = 0; j < 2; ++j) {
            bfr[2 + j][0] = *(const bf16x8*)(bRd + offk0 + (2 + j) * 2048);
            bfr[2 + j][1] = *(const bf16x8*)(bRd + offk1 + (2 + j) * 2048);
        }
        if (notlast) {
#pragma unroll
            for (int p = 0; p < 4; ++p) {
                async16(gB[p], bSt + (wid * 4 + p) * 1024);
                gB[p] += 64;
            }
        }
        __builtin_amdgcn_s_barrier();
        asm volatile("s_waitcnt lgkmcnt(0)" ::: "memory");
        __builtin_amdgcn_sched_barrier(0);
        __builtin_amdgcn_s_setprio(1);
#pragma unroll
        for (int i = 0; i < 4; ++i)
#pragma unroll
            for (int j = 0; j < 2; ++j)
#pragma unroll
                for (int kk = 0; kk < 2; ++kk)
                    acc[i][2 + j] = mfma16(af[i][kk], bfr[2 + j][kk], acc[i][2 + j]);
        __builtin_amdgcn_s_setprio(0);
        __builtin_amdgcn_s_barrier();

        // ================= phase 2: Q(1,0) =================
#pragma unroll
        for (int i = 0; i < 4; ++i) {
            af[i][0] = *(const bf16x8*)(aRd + offk0 + (4 + i) * 2048);
            af[i][1] = *(const bf16x8*)(aRd + offk1 + (4 + i) * 2048);
        }
        __builtin_amdgcn_s_barrier();
        asm volatile("s_waitcnt lgkmcnt(0)" ::: "memory");
        __builtin_amdgcn_sched_barrier(0);
        __builtin_amdgcn_s_setprio(1);
#pragma unroll
        for (int i = 0; i < 4; ++i)
#pragma unroll
            for (int j = 0; j < 2; ++j)
#pragma unroll
                for (int kk = 0; kk < 2; ++kk)
                    acc[4 + i][j] = mfma16(af[i][kk], bfr[j][kk], acc[4 + i][j]);
        __builtin_amdgcn_s_setprio(0);
        __builtin_amdgcn_s_barrier();

        // ================= phase 3: Q(1,1) =================
        __builtin_amdgcn_s_setprio(1);
#pragma unroll
        for (int i = 0; i < 4; ++i)
#pragma unroll
            for (int j = 0; j < 2; ++j)
#pragma unroll
                for (int kk = 0; kk < 2; ++kk)
                    acc[4 + i][2 + j] = mfma16(af[i][kk], bfr[2 + j][kk], acc[4 + i][2 + j]);
        __builtin_amdgcn_s_setprio(0);
        asm volatile("s_waitcnt vmcnt(0)" ::: "memory");
        __builtin_amdgcn_s_barrier();
        cur ^= 32768;
    }

    // ---- epilogue: 8 chunks of 32 rows via LDS cs=[32][264] bf16 ----
    // FULLY unrolled: all acc indices compile-time constants (rule #20).
    __bf16* cs = (__bf16*)smem;
#pragma unroll
    for (int c = 0; c < 8; ++c) {
        __syncthreads();
        if (wr == (c >> 2)) {
#pragma unroll
            for (int mloc = 0; mloc < 2; ++mloc) {
#pragma unroll
                for (int ni = 0; ni < 4; ++ni) {
                    int col = wc * 64 + ni * 16 + l15;
#pragma unroll
                    for (int rg = 0; rg < 4; ++rg)
                        cs[(mloc * 16 + quad * 4 + rg) * 264 + col] =
                            (__bf16)acc[(c & 3) * 2 + mloc][ni][rg];
                }
            }
        }
        __syncthreads();
#pragma unroll
        for (int p = 0; p < 2; ++p) {
            int row  = p * 16 + (tid >> 5);
            int colc = tid & 31;
            bf16x8 v = *(const bf16x8*)&cs[row * 264 + colc * 8];
            *(bf16x8*)&Cout[(size_t)(bm + c * 32 + row) * ldc + bn + colc * 8] = v;
        }
    }
}

// ---------------------------------------------------------------------------
// GEMM: C[M x N] = A[M x K] * Bt[N x K]^T (+ bias); bf16 in, fp32 acc.
// 128x128 tile, BK=32, 4 waves, 16x16x32 MFMA, async16 staging w/ XOR swizzle.
// Epilogue: stage through LDS (aliases lsA/lsB), store coalesced row segments.
// MODE 0: C bf16, no bias. MODE 1: C/bias dtype per flag.
// ---------------------------------------------------------------------------
template <int MODE>
__global__ __launch_bounds__(256)
void gemm_bt(const __bf16* __restrict__ A, int lda,
             const __bf16* __restrict__ Bt,
             const void* __restrict__ bias,
             void* __restrict__ Cout, int ldc,
             int K, const int* __restrict__ flag) {
    __shared__ __align__(16) char smem[16384];
    __bf16* lsA = (__bf16*)smem;            // 128 x 32
    __bf16* lsB = (__bf16*)(smem + 8192);   // 128 x 32
    const int tid  = threadIdx.x;
    const int wid  = tid >> 6;
    const int lane = tid & 63;
    const int quad = lane >> 4;
    const int l15  = lane & 15;
    const int bm = blockIdx.x * 128;
    const int bn = blockIdx.y * 128;
    const int wm = (wid & 1) * 64;
    const int wn = (wid >> 1) * 64;
    const int srow  = lane >> 2;
    const int sslot = lane & 3;

    f32x4 acc[4][4];
#pragma unroll
    for (int i = 0; i < 4; ++i)
#pragma unroll
        for (int j = 0; j < 4; ++j) acc[i][j] = (f32x4)0.0f;

    for (int k0 = 0; k0 < K; k0 += 32) {
        __syncthreads();
#pragma unroll
        for (int is = 0; is < 2; ++is) {
            int r  = is * 64 + wid * 16 + srow;
            int gc = k0 + ((sslot ^ ((r >> 1) & 3)) << 3);
            async16(A + (size_t)(bm + r) * lda + gc, &lsA[(is * 64 + wid * 16) * 32]);
        }
#pragma unroll
        for (int is = 0; is < 2; ++is) {
            int r  = is * 64 + wid * 16 + srow;
            int gc = k0 + ((sslot ^ ((r >> 1) & 3)) << 3);
            async16(Bt + (size_t)(bn + r) * K + gc, &lsB[(is * 64 + wid * 16) * 32]);
        }
        __syncthreads();

        bf16x8 af[4], bfr[4];
#pragma unroll
        for (int mi = 0; mi < 4; ++mi) {
            int r = wm + mi * 16 + l15;
            af[mi] = *(const bf16x8*)&lsA[r * 32 + (quad ^ ((r >> 1) & 3)) * 8];
        }
#pragma unroll
        for (int ni = 0; ni < 4; ++ni) {
            int r = wn + ni * 16 + l15;
            bfr[ni] = *(const bf16x8*)&lsB[r * 32 + (quad ^ ((r >> 1) & 3)) * 8];
        }
#pragma unroll
        for (int mi = 0; mi < 4; ++mi)
#pragma unroll
            for (int ni = 0; ni < 4; ++ni)
                acc[mi][ni] = mfma16(af[mi], bfr[ni], acc[mi][ni]);
    }

    // ---- epilogue: bias add in-register, then LDS-staged coalesced stores ----
    const int f = (MODE == 1) ? *flag : 0;
    if (MODE == 1) {
#pragma unroll
        for (int ni = 0; ni < 4; ++ni) {
            int col = bn + wn + ni * 16 + l15;
            float bv = f ? ((const float*)bias)[col] : (float)((const __bf16*)bias)[col];
#pragma unroll
            for (int mi = 0; mi < 4; ++mi)
#pragma unroll
                for (int rg = 0; rg < 4; ++rg) acc[mi][ni][rg] += bv;
        }
    }

    if (MODE == 0 || !f) {
        // bf16 output: 4 chunks of 32 rows; cs = [32][136] bf16 (8704 B)
        __bf16* cs = (__bf16*)smem;
#pragma unroll
        for (int c = 0; c < 4; ++c) {
            __syncthreads();
            if (wm == (c >> 1) * 64) {
                int mb = (c & 1) * 2;
#pragma unroll
                for (int mloc = 0; mloc < 2; ++mloc) {
                    int rowc = mloc * 16 + quad * 4;
#pragma unroll
                    for (int ni = 0; ni < 4; ++ni) {
                        int col = wn + ni * 16 + l15;
#pragma unroll
                        for (int rg = 0; rg < 4; ++rg)
                            cs[(rowc + rg) * 136 + col] = (__bf16)acc[mb + mloc][ni][rg];
                    }
                }
            }
            __syncthreads();
#pragma unroll
            for (int p = 0; p < 2; ++p) {
                int row  = p * 16 + (tid >> 4);
                int colc = tid & 15;
                bf16x8 v = *(const bf16x8*)&cs[row * 136 + colc * 8];
                *(bf16x8*)((__bf16*)Cout + (size_t)(bm + c * 32 + row) * ldc + bn + colc * 8) = v;
            }
        }
    } else {
        // fp32 output: 8 chunks of 16 rows; cs = [16][132] float (8448 B)
        float* cs = (float*)smem;
#pragma unroll
        for (int c = 0; c < 8; ++c) {
            __syncthreads();
            if (wm == (c >> 2) * 64) {
                int mi = c & 3;
                int rowc = quad * 4;
#pragma unroll
                for (int ni = 0; ni < 4; ++ni) {
                    int col = wn + ni * 16 + l15;
#pragma unroll
                    for (int rg = 0; rg < 4; ++rg)
                        cs[(rowc + rg) * 132 + col] = acc[mi][ni][rg];
                }
            }
            __syncthreads();
#pragma unroll
            for (int p = 0; p < 2; ++p) {
                int row  = p * 8 + (tid >> 5);
                int colc = tid & 31;
                float4 v = *(const float4*)&cs[row * 132 + colc * 4];
                *(float4*)((float*)Cout + (size_t)(bm + c * 16 + row) * ldc + bn + colc * 4) = v;
            }
        }
    }
}

// ---------------------------------------------------------------------------
// Flash attention, S^T formulation, async16 staging. Grid (B*H, N/128) --
// bh is blockIdx.x so id%8 = bh%8: all q-tiles of a head pin to one XCD.
// Round 7: register-relaxed, address-hoisted, half-split K-step.
// ---------------------------------------------------------------------------
__global__ __launch_bounds__(256, 2)
void attn(const __bf16* qkv, const __bf16* __restrict__ vt,
          const int* __restrict__ perm, __bf16* O, int ldo) {
    __shared__ __align__(16) char smem[38912];
    __bf16* Qs = (__bf16*)smem;              // 128 x 64 (alive until qf loaded)
    __bf16* Ks = (__bf16*)smem;              // 64 x 64  (aliases Qs)
    __bf16* Vs = (__bf16*)(smem + 8192);     // 64 x 64  (rows = dh)
    __bf16* Ps = (__bf16*)(smem + 16384);    // 4 waves x [32 x 88]

    const int tid  = threadIdx.x;
    const int wid  = tid >> 6;
    const int lane = tid & 63;
    const int quad = lane >> 4;
    const int l15  = lane & 15;
    const int bh = blockIdx.x;
    const int q0 = blockIdx.y * 128;
    const int b = bh / 12, h = bh % 12;
    const size_t row_base = (size_t)b * 1024;
    const int qcol = h * 64;
    const int kcol = 768 + h * 64;
    const int srow8  = lane >> 3;
    const int sslot8 = lane & 7;
    __bf16* Pw = Ps + wid * (32 * 88);

    // ---- stage Q (perm-gathered rows) ----
#pragma unroll
    for (int is = 0; is < 4; ++is) {
        int r = is * 32 + wid * 8 + srow8;
        int gr = perm[q0 + r];
        int chunk = sslot8 ^ (r & 7);
        async16(qkv + (row_base + gr) * 2304 + qcol + chunk * 8,
                &Qs[(is * 32 + wid * 8) * 64]);
    }
    __syncthreads();

    bf16x8 qf[2][2];
#pragma unroll
    for (int mi = 0; mi < 2; ++mi) {
        int r = wid * 32 + mi * 16 + l15;
#pragma unroll
        for (int ks = 0; ks < 2; ++ks)
            qf[mi][ks] = *(const bf16x8*)&Qs[r * 64 + (((ks * 4 + quad) ^ (r & 7)) * 8)];
    }

    // ---- loop-invariant LDS element offsets ----
    const int off0 = l15 * 64 + (((0 * 4 + quad) ^ (l15 & 7)) * 8); // ks/ks2 = 0
    const int off1 = l15 * 64 + (((1 * 4 + quad) ^ (l15 & 7)) * 8); // ks/ks2 = 1
    const int pwb  = l15 * 88 + quad * 4;   // + mi*1408 + ki*16 (immediates)
    const int pfb  = l15 * 88 + quad * 8;   // + mi*1408 + ks2*32 (immediates)

    // ---- held global staging pointers (incremented per kt) ----
    const int rK = wid * 8 + srow8;                 // +32 for second chunk
    const int ck = sslot8 ^ (rK & 7);               // (is*32)&7 == 0
    const __bf16* kg0 = qkv + (row_base + rK) * 2304 + kcol + ck * 8;
    const __bf16* kg1 = kg0 + (size_t)32 * 2304;
    const __bf16* vg0 = vt + ((size_t)bh * 64 + rK) * 1024 + ck * 8;
    const __bf16* vg1 = vg0 + (size_t)32 * 1024;

    f32x4 acco[2][4];
#pragma unroll
    for (int mi = 0; mi < 2; ++mi)
#pragma unroll
        for (int ni = 0; ni < 4; ++ni) acco[mi][ni] = (f32x4)0.0f;
    float lsum[2] = {0.0f, 0.0f};

    const float cfac = 0.125f * 1.44269504088896340736f;

    for (int kt = 0; kt < 16; ++kt) {
        __syncthreads();
        async16(kg0, &Ks[(wid * 8) * 64]);
        async16(kg1, &Ks[(32 + wid * 8) * 64]);
        async16(vg0, &Vs[(wid * 8) * 64]);
        async16(vg1, &Vs[(32 + wid * 8) * 64]);
        kg0 += (size_t)64 * 2304;
        kg1 += (size_t)64 * 2304;
        vg0 += 64;
        vg1 += 64;
        __syncthreads();

#pragma unroll
        for (int half = 0; half < 2; ++half) {
            // ---- QK^T for ki = half*2 .. half*2+1 ----
            f32x4 accs[2][2];
#pragma unroll
            for (int ki = 0; ki < 2; ++ki)
#pragma unroll
                for (int mi = 0; mi < 2; ++mi) accs[ki][mi] = (f32x4)0.0f;
#pragma unroll
            for (int ks = 0; ks < 2; ++ks) {
                const int off = ks ? off1 : off0;
                bf16x8 kf0 = *(const bf16x8*)&Ks[(half * 2 + 0) * 1024 + off];
                bf16x8 kf1 = *(const bf16x8*)&Ks[(half * 2 + 1) * 1024 + off];
                accs[0][0] = mfma16(kf0, qf[0][ks], accs[0][0]);
                accs[0][1] = mfma16(kf0, qf[1][ks], accs[0][1]);
                accs[1][0] = mfma16(kf1, qf[0][ks], accs[1][0]);
                accs[1][1] = mfma16(kf1, qf[1][ks], accs[1][1]);
            }

            // ---- softmax (static bias -8; cancels in normalization) ----
#pragma unroll
            for (int ki = 0; ki < 2; ++ki)
#pragma unroll
                for (int mi = 0; mi < 2; ++mi) {
                    bf16x4 pk;
                    float s0 = __builtin_amdgcn_exp2f(accs[ki][mi][0] * cfac - 8.0f);
                    float s1 = __builtin_amdgcn_exp2f(accs[ki][mi][1] * cfac - 8.0f);
                    float s2 = __builtin_amdgcn_exp2f(accs[ki][mi][2] * cfac - 8.0f);
                    float s3 = __builtin_amdgcn_exp2f(accs[ki][mi][3] * cfac - 8.0f);
                    pk[0] = (__bf16)s0; pk[1] = (__bf16)s1;
                    pk[2] = (__bf16)s2; pk[3] = (__bf16)s3;
                    lsum[mi] += (s0 + s1) + (s2 + s3);
                    *(bf16x4*)&Pw[pwb + mi * 1408 + (half * 2 + ki) * 16] = pk;
                }

            // ---- PV for ks2 = half (same-wave LDS RAW; lgkmcnt orders it) ----
            {
                bf16x8 pf0 = *(const bf16x8*)&Pw[pfb + 0 * 1408 + half * 32];
                bf16x8 pf1 = *(const bf16x8*)&Pw[pfb + 1 * 1408 + half * 32];
                const int offv = half ? off1 : off0;
#pragma unroll
                for (int ni = 0; ni < 4; ++ni) {
                    bf16x8 vf = *(const bf16x8*)&Vs[ni * 1024 + offv];
                    acco[0][ni] = mfma16(pf0, vf, acco[0][ni]);
                    acco[1][ni] = mfma16(pf1, vf, acco[1][ni]);
                }
            }
        }
    }

#pragma unroll
    for (int off = 16; off < 64; off <<= 1) {
        lsum[0] += __shfl_xor(lsum[0], off, 64);
        lsum[1] += __shfl_xor(lsum[1], off, 64);
    }

#pragma unroll
    for (int mi = 0; mi < 2; ++mi) {
#pragma unroll
        for (int rg = 0; rg < 4; ++rg) {
            float inv = 1.0f / __shfl(lsum[mi], quad * 4 + rg, 64);
            int orow = q0 + wid * 32 + mi * 16 + quad * 4 + rg;
#pragma unroll
            for (int ni = 0; ni < 4; ++ni) {
                int ocol = h * 64 + ni * 16 + l15;
                O[(row_base + orow) * (size_t)ldo + ocol] = (__bf16)(acco[mi][ni][rg] * inv);
            }
        }
    }
}

// ---------------------------------------------------------------------------
// Workspace layout (bytes), total ~130.5 MB (see round-3 comment).
// ---------------------------------------------------------------------------
extern "C" void kernel_launch(void* const* d_in, const int* in_sizes, int n_in,
                              void* d_out, int out_size, void* d_ws, size_t ws_size,
                              hipStream_t stream) {
    (void)in_sizes; (void)n_in; (void)out_size; (void)ws_size;
    const void* x_raw    = d_in[0];
    const void* Wqkv_raw = d_in[1];
    const void* Wout_raw = d_in[2];
    const void* bout_raw = d_in[3];
    const int*  perm     = (const int*)d_in[4];

    char* ws = (char*)d_ws;
    int*    flag = (int*)ws;
    __bf16* Xc   = (__bf16*)(ws + 256);
    __bf16* QKV  = (__bf16*)(ws + 25166080);
    __bf16* Vt   = (__bf16*)(ws + 100663552);
    __bf16* Wqt  = (__bf16*)(ws + 125829376);
    __bf16* Wot  = (__bf16*)(ws + 129368320);
    __bf16* Obuf = QKV + 1536; // O[n][768] in QKV's V columns, ld 2304

    detect_dtype<<<1, 256, 0, stream>>>((const unsigned short*)x_raw, flag);
    convert_to_bf16<<<2048, 256, 0, stream>>>(x_raw, Xc, 16384 * 768 / 4, flag);
    transpose_dyn<<<dim3(36, 12), dim3(64, 4), 0, stream>>>(Wqkv_raw, Wqt, 768, 2304, flag);
    transpose_dyn<<<dim3(12, 12), dim3(64, 4), 0, stream>>>(Wout_raw, Wot, 768, 768, flag);
    gemm256_bt<<<dim3(64, 9), 512, 0, stream>>>(Xc, 768, Wqt, 768, QKV, 2304, 768);
    transpose_v<<<dim3(16, 192), dim3(64, 4), 0, stream>>>(QKV, Vt);
    attn<<<dim3(192, 8), 256, 0, stream>>>(QKV, Vt, perm, Obuf, 2304);
    gemm_bt<1><<<dim3(128, 6), 256, 0, stream>>>(Obuf, 2304, Wot, bout_raw, d_out, 768, 768, flag);
}